// Round 15
// baseline (588.543 us; speedup 1.0000x reference)
//
#include <hip/hip_runtime.h>
#include <math.h>

// Problem: B=2, S=2048, d=1024, h=8, hd=128, hv=256, vd=2048, f=4096
#define RTOT 4096
#define SEQQ 2048

typedef unsigned int uint32;
typedef __attribute__((ext_vector_type(4))) float f32x4;
typedef __attribute__((ext_vector_type(8))) short bf16x8;

__device__ __forceinline__ unsigned short f2bf(float f) {
  unsigned int u = __float_as_uint(f);
  u = (u + 0x7FFFu + ((u >> 16) & 1u)) >> 16;
  return (unsigned short)u;
}
__device__ __forceinline__ float bf2f(unsigned short h) {
  return __uint_as_float(((unsigned int)h) << 16);
}
__device__ __forceinline__ void gld16(const void* g, void* l) {
  __builtin_amdgcn_global_load_lds(
      (const __attribute__((address_space(1))) uint32*)g,
      (__attribute__((address_space(3))) uint32*)l, 16, 0, 0);
}
__device__ __forceinline__ void bar() {
  asm volatile("" ::: "memory");
  __builtin_amdgcn_s_barrier();
  asm volatile("" ::: "memory");
}
#define VMCNT(n) asm volatile("s_waitcnt vmcnt(" #n ")" ::: "memory")

// ---- device transpose tile body: f32[R][C] (+z) -> bf16[C][R], opt. perm ----
__device__ __forceinline__ void tr_tile(
    const float* __restrict__ in, unsigned short* __restrict__ out,
    int R, int C, int perm, int bx, int by, int z) {
  __shared__ float t[32][33];
  in  += (size_t)z * R * C;
  out += (size_t)z * C * R;
  int r0 = bx * 32, c0 = by * 32;
  int tx = threadIdx.x & 31, ty = threadIdx.x >> 5;
  #pragma unroll
  for (int i = 0; i < 4; ++i) {
    int r = ty + i * 8;
    t[r][tx] = in[(size_t)(r0 + r) * C + c0 + tx];
  }
  __syncthreads();
  #pragma unroll
  for (int i = 0; i < 4; ++i) {
    int cc = c0 + ty + i * 8;
    if (perm) cc = 64 * (cc >> 6) + ((cc & 1) << 5) + ((cc & 63) >> 1);
    out[(size_t)cc * R + r0 + tx] = f2bf(t[tx][ty + i * 8]);
  }
}

// ---- tabgen body ----
__device__ __forceinline__ void tab_body(float* __restrict__ tab, int blk) {
  int i = blk * 256 + threadIdx.x;   // 131072
  int pos = i >> 6, j = i & 63;
  float bs = (2.f * (float)j + 51.2f) * (1.f / 179.2f);
  float e = (float)pos * (1.f / 512.f);
  float sc = exp2f(e * log2f(bs));
  float invf = exp2f(-(float)j * (13.287712379549449f / 64.f));
  float su, cu;
  sincosf((float)pos * invf, &su, &cu);
  tab[i]            = cu * sc;
  tab[131072 + i]   = su * sc;
  float si = 1.f / sc;
  tab[262144 + i]   = cu * si;
  tab[393216 + i]   = su * si;
}

// ---- LayerNorm row body ----
__device__ __forceinline__ void ln_row(const float* __restrict__ x,
    const float* __restrict__ w, const float* __restrict__ b,
    unsigned short* __restrict__ out, int row) {
  __shared__ float red[2][4];
  int tid = threadIdx.x;
  const float* xr = x + (size_t)row * 1024;
  float4 v = *(const float4*)(xr + tid * 4);
  float s  = v.x + v.y + v.z + v.w;
  float ss = v.x*v.x + v.y*v.y + v.z*v.z + v.w*v.w;
  #pragma unroll
  for (int o = 32; o > 0; o >>= 1) { s += __shfl_down(s, o); ss += __shfl_down(ss, o); }
  int wid = tid >> 6;
  if ((tid & 63) == 0) { red[0][wid] = s; red[1][wid] = ss; }
  __syncthreads();
  float st  = red[0][0] + red[0][1] + red[0][2] + red[0][3];
  float sst = red[1][0] + red[1][1] + red[1][2] + red[1][3];
  float mu   = st * (1.f / 1024.f);
  float var  = sst * (1.f / 1024.f) - mu * mu;
  float rstd = rsqrtf(var + 1e-5f);
  float4 wv = *(const float4*)(w + tid * 4);
  float4 bv = *(const float4*)(b + tid * 4);
  unsigned short o0 = f2bf((v.x - mu) * rstd * wv.x + bv.x);
  unsigned short o1 = f2bf((v.y - mu) * rstd * wv.y + bv.y);
  unsigned short o2 = f2bf((v.z - mu) * rstd * wv.z + bv.z);
  unsigned short o3 = f2bf((v.w - mu) * rstd * wv.w + bv.w);
  ushort4 o4 = make_ushort4(o0, o1, o2, o3);
  *(ushort4*)(out + (size_t)row * 1024 + tid * 4) = o4;
}

// ---- cvt body ----
__device__ __forceinline__ void cvt_body(const float* __restrict__ in,
    unsigned short* __restrict__ out, int blk) {
  int i = blk * 256 + threadIdx.x;
  const float4* p = (const float4*)(in + (size_t)i * 8);
  float4 a = p[0], b = p[1];
  bf16x8 v;
  v[0] = (short)f2bf(a.x); v[1] = (short)f2bf(a.y); v[2] = (short)f2bf(a.z); v[3] = (short)f2bf(a.w);
  v[4] = (short)f2bf(b.x); v[5] = (short)f2bf(b.y); v[6] = (short)f2bf(b.z); v[7] = (short)f2bf(b.w);
  *(bf16x8*)(out + (size_t)i * 8) = v;
}

// ---- prep1: W transposes + tabgen + LN1(X) in one launch (12800 blocks) ----
__global__ __launch_bounds__(256) void prep1(
    const float* Wq, const float* Wk, const float* Wg, const float* Wv,
    const float* Wo, unsigned short* WqkgT, unsigned short* WvT,
    unsigned short* WoT, float* tab,
    const float* X, const float* ln1w, const float* ln1b, unsigned short* hbuf) {
  int idx = blockIdx.x;
  if (idx < 1024)      { tr_tile(Wq, WqkgT,               1024, 128, 1, idx & 31, (idx >> 5) & 3, idx >> 7); }
  else if (idx < 2048) { int i = idx - 1024; tr_tile(Wk, WqkgT + 1024 * 1024, 1024, 128, 1, i & 31, (i >> 5) & 3, i >> 7); }
  else if (idx < 4096) { int i = idx - 2048; tr_tile(Wg, WqkgT + 2048 * 1024, 1024, 2048, 0, i & 31, i >> 5, 0); }
  else if (idx < 6144) { int i = idx - 4096; tr_tile(Wv, WvT, 1024, 256, 0, i & 31, (i >> 5) & 7, i >> 8); }
  else if (idx < 8192) { int i = idx - 6144; tr_tile(Wo, WoT, 2048, 1024, 0, i & 63, i >> 6, 0); }
  else if (idx < 8704) { tab_body(tab, idx - 8192); }
  else                 { ln_row(X, ln1w, ln1b, hbuf, idx - 8704); }
}

// ---- prep2: cross weights + cvt(mem) + LN2(out) (14336 blocks) ----
__global__ __launch_bounds__(256) void prep2(
    const float* cWq, const float* cWg, const float* cWk, const float* cWv,
    const float* cWo, unsigned short* cQGT, unsigned short* cWkT,
    unsigned short* cWvT, unsigned short* cWoT,
    const float* mem, unsigned short* mem16,
    const float* out, const float* ln2w, const float* ln2b, unsigned short* hbuf) {
  int idx = blockIdx.x;
  if (idx < 1024)       { tr_tile(cWq, cQGT,               1024, 128, 1, idx & 31, (idx >> 5) & 3, idx >> 7); }
  else if (idx < 3072)  { int i = idx - 1024; tr_tile(cWg, cQGT + 1024 * 1024, 1024, 2048, 0, i & 31, i >> 5, 0); }
  else if (idx < 4096)  { int i = idx - 3072; tr_tile(cWk, cWkT, 1024, 128, 1, i & 31, (i >> 5) & 3, i >> 7); }
  else if (idx < 6144)  { int i = idx - 4096; tr_tile(cWv, cWvT, 1024, 256, 0, i & 31, (i >> 5) & 7, i >> 8); }
  else if (idx < 8192)  { int i = idx - 6144; tr_tile(cWo, cWoT, 2048, 1024, 0, i & 63, i >> 6, 0); }
  else if (idx < 10240) { cvt_body(mem, mem16, idx - 8192); }
  else                  { ln_row(out, ln2w, ln2b, hbuf, idx - 10240); }
}

// ---- prep3: FFN weights + LN2(out) (12288 blocks) ----
__global__ __launch_bounds__(256) void prep3(
    const float* W1, const float* W2, unsigned short* W1T, unsigned short* W2T,
    const float* out, const float* ln2w, const float* ln2b, unsigned short* hbuf) {
  int idx = blockIdx.x;
  if (idx < 4096)      { tr_tile(W1, W1T, 1024, 4096, 0, idx & 31, idx >> 5, 0); }
  else if (idx < 8192) { int i = idx - 4096; tr_tile(W2, W2T, 4096, 1024, 0, i & 127, i >> 7, 0); }
  else                 { ln_row(out, ln2w, ln2b, hbuf, idx - 8192); }
}

// ---------------- epilogues ----------------
enum { EPI_F32_RES = 0, EPI_BF16 = 1, EPI_XPOS = 2, EPI_GELU = 4, EPI_BRES = 5,
       EPI_QKG = 6, EPI_QG = 7 };

struct EpiP {
  void* C; int ldc;
  const float* bias; const float* resid;
  const float* tab;
  unsigned short* oQ; unsigned short* oK; unsigned short* oG;
};

template<int EPI>
__device__ __forceinline__ void epi_store(size_t m, int n, int N0, float v, const EpiP& P) {
  if constexpr (EPI == EPI_BF16) {
    ((unsigned short*)P.C)[m * P.ldc + n] = f2bf(v);
  } else if constexpr (EPI == EPI_GELU) {
    v += P.bias[n];
    v = 0.5f * v * (1.f + erff(v * 0.70710678f));
    ((unsigned short*)P.C)[m * P.ldc + n] = f2bf(v);
  } else if constexpr (EPI == EPI_BRES) {
    v += P.bias[n] + P.resid[m * P.ldc + n];
    ((float*)P.C)[m * P.ldc + n] = v;
  } else {  // EPI_F32_RES
    v += P.resid[m * P.ldc + n];
    ((float*)P.C)[m * P.ldc + n] = v;
  }
}

// -- MFMA GEMM 128x128, BK=64 (2 subtiles), dbuf, counted vmcnt, XCD swizzle --
template<int EPI>
__global__ __launch_bounds__(256) void gemm_mfma(
    const unsigned short* __restrict__ A, int lda,
    const unsigned short* __restrict__ Bt, int ldb, int K, int nbx, EpiP P) {
  __shared__ __align__(16) unsigned short As[2][2][128 * 32];
  __shared__ __align__(16) unsigned short Bs[2][2][128 * 32];
  const int tid = threadIdx.x, w = tid >> 6, lane = tid & 63;
  int q8 = (int)gridDim.x >> 3;
  int sbid = ((int)blockIdx.x & 7) * q8 + ((int)blockIdx.x >> 3);
  int by = sbid / nbx, bx = sbid - by * nbx;
  const int M0 = by * 128, N0 = bx * 128;
  const int fr = lane & 15, fs = lane >> 4;
  const int srow = lane >> 2, sp = lane & 3;

  f32x4 zf = {0.f, 0.f, 0.f, 0.f};
  f32x4 acc[4][4];
  #pragma unroll
  for (int i = 0; i < 4; ++i)
    #pragma unroll
    for (int j = 0; j < 4; ++j) acc[i][j] = zf;

  auto STAGE = [&](int buf, int k0) {
    #pragma unroll
    for (int kk = 0; kk < 2; ++kk)
      #pragma unroll
      for (int c = 0; c < 4; ++c) {
        int ch = w * 4 + c;
        int cc = ch & 7;
        int row = cc * 16 + srow;
        int so = sp ^ ((row >> 1) & 3);
        if (ch < 8) gld16(A  + (size_t)(M0 + row) * lda + k0 + kk * 32 + so * 8, &As[buf][kk][cc * 512]);
        else        gld16(Bt + (size_t)(N0 + row) * ldb + k0 + kk * 32 + so * 8, &Bs[buf][kk][cc * 512]);
      }
  };

  const int NT = K >> 6;
  STAGE(0, 0);
  int cur = 0;
  for (int t = 0; t < NT; ++t) {
    if (t + 1 < NT) { STAGE(cur ^ 1, (t + 1) * 64); VMCNT(8); }
    else            { VMCNT(0); }
    bar();
    #pragma unroll
    for (int kk = 0; kk < 2; ++kk) {
      bf16x8 af[4], bfr[4];
      #pragma unroll
      for (int mi = 0; mi < 4; ++mi) {
        int row = (w >> 1) * 64 + mi * 16 + fr;
        af[mi] = *(const bf16x8*)(&As[cur][kk][row * 32 + (fs ^ ((row >> 1) & 3)) * 8]);
      }
      #pragma unroll
      for (int ni = 0; ni < 4; ++ni) {
        int row = (w & 1) * 64 + ni * 16 + fr;
        bfr[ni] = *(const bf16x8*)(&Bs[cur][kk][row * 32 + (fs ^ ((row >> 1) & 3)) * 8]);
      }
      #pragma unroll
      for (int mi = 0; mi < 4; ++mi)
        #pragma unroll
        for (int ni = 0; ni < 4; ++ni)
          acc[mi][ni] = __builtin_amdgcn_mfma_f32_16x16x32_bf16(af[mi], bfr[ni], acc[mi][ni], 0, 0, 0);
    }
    bar();
    cur ^= 1;
  }

  #pragma unroll
  for (int mi = 0; mi < 4; ++mi)
    #pragma unroll
    for (int r = 0; r < 4; ++r) {
      size_t m = M0 + (w >> 1) * 64 + mi * 16 + fs * 4 + r;
      #pragma unroll
      for (int ni = 0; ni < 4; ++ni) {
        int n = N0 + (w & 1) * 64 + ni * 16 + fr;
        epi_store<EPI>(m, n, N0, acc[mi][ni][r], P);
      }
    }
}

// -- MFMA GEMM 128x64, BK=64 (2 subtiles), dbuf, counted vmcnt, XCD swizzle --
template<int EPI>
__global__ __launch_bounds__(256) void gemm_bn64(
    const unsigned short* __restrict__ A, int lda,
    const unsigned short* __restrict__ Bt, int ldb, int K, int nbx, EpiP P) {
  __shared__ __align__(16) unsigned short As[2][2][128 * 32];
  __shared__ __align__(16) unsigned short Bs[2][2][64 * 32];
  const int tid = threadIdx.x, w = tid >> 6, lane = tid & 63;
  int q8 = (int)gridDim.x >> 3;
  int sbid = ((int)blockIdx.x & 7) * q8 + ((int)blockIdx.x >> 3);
  int by = sbid / nbx, bx = sbid - by * nbx;
  const int M0 = by * 128, N0 = bx * 64;
  const int fr = lane & 15, fs = lane >> 4;
  const int srow = lane >> 2, sp = lane & 3;

  f32x4 zf = {0.f, 0.f, 0.f, 0.f};
  f32x4 acc[2][4];
  #pragma unroll
  for (int i = 0; i < 2; ++i)
    #pragma unroll
    for (int j = 0; j < 4; ++j) acc[i][j] = zf;

  auto STAGE = [&](int buf, int k0) {
    #pragma unroll
    for (int kk = 0; kk < 2; ++kk)
      #pragma unroll
      for (int c = 0; c < 3; ++c) {
        int ch = w * 3 + c;
        if (ch < 8) {
          int row = ch * 16 + srow;
          int so = sp ^ ((row >> 1) & 3);
          gld16(A + (size_t)(M0 + row) * lda + k0 + kk * 32 + so * 8, &As[buf][kk][ch * 512]);
        } else {
          int bch = ch - 8;
          int row = bch * 16 + srow;
          int so = sp ^ ((row >> 1) & 3);
          gld16(Bt + (size_t)(N0 + row) * ldb + k0 + kk * 32 + so * 8, &Bs[buf][kk][bch * 512]);
        }
      }
  };

  const int NT = K >> 6;
  STAGE(0, 0);
  int cur = 0;
  for (int t = 0; t < NT; ++t) {
    if (t + 1 < NT) { STAGE(cur ^ 1, (t + 1) * 64); VMCNT(6); }
    else            { VMCNT(0); }
    bar();
    #pragma unroll
    for (int kk = 0; kk < 2; ++kk) {
      bf16x8 af[2], bfr[4];
      #pragma unroll
      for (int mi = 0; mi < 2; ++mi) {
        int row = w * 32 + mi * 16 + fr;
        af[mi] = *(const bf16x8*)(&As[cur][kk][row * 32 + (fs ^ ((row >> 1) & 3)) * 8]);
      }
      #pragma unroll
      for (int ni = 0; ni < 4; ++ni) {
        int row = ni * 16 + fr;
        bfr[ni] = *(const bf16x8*)(&Bs[cur][kk][row * 32 + (fs ^ ((row >> 1) & 3)) * 8]);
      }
      #pragma unroll
      for (int mi = 0; mi < 2; ++mi)
        #pragma unroll
        for (int ni = 0; ni < 4; ++ni)
          acc[mi][ni] = __builtin_amdgcn_mfma_f32_16x16x32_bf16(af[mi], bfr[ni], acc[mi][ni], 0, 0, 0);
    }
    bar();
    cur ^= 1;
  }

  if constexpr (EPI == EPI_XPOS) {
    int gsel = (N0 >> 6) & 1;
    #pragma unroll
    for (int mi = 0; mi < 2; ++mi)
      #pragma unroll
      for (int r = 0; r < 4; ++r) {
        size_t m = M0 + w * 32 + mi * 16 + fs * 4 + r;
        int pos = (int)(m & (SEQQ - 1));
        #pragma unroll
        for (int ni = 0; ni < 2; ++ni) {
          int j = gsel * 32 + ni * 16 + fr;
          float cs = P.tab[pos * 64 + j], sn = P.tab[131072 + pos * 64 + j];
          float ve = acc[mi][ni][r], vo = acc[mi][ni + 2][r];
          unsigned short* dst = (unsigned short*)P.C;
          dst[m * P.ldc + N0 + ni * 16 + fr]       = f2bf(ve * cs - vo * sn);
          dst[m * P.ldc + N0 + (ni + 2) * 16 + fr] = f2bf(vo * cs + ve * sn);
        }
      }
  } else {
    #pragma unroll
    for (int mi = 0; mi < 2; ++mi)
      #pragma unroll
      for (int r = 0; r < 4; ++r) {
        size_t m = M0 + w * 32 + mi * 16 + fs * 4 + r;
        #pragma unroll
        for (int ni = 0; ni < 4; ++ni) {
          int n = N0 + ni * 16 + fr;
          epi_store<EPI>(m, n, N0, acc[mi][ni][r], P);
        }
      }
  }
}

// ---------------- 256x256 8-wave GEMM, 4-deep counted-vmcnt pipeline --------
template<int EPI>
__global__ __launch_bounds__(512, 2) void gemm256(
    const unsigned short* __restrict__ A,
    const unsigned short* __restrict__ Bt,
    int nbx, EpiP P) {
  __shared__ __align__(16) unsigned short lds[4][2][8192];
  const int tid = threadIdx.x, w = tid >> 6, lane = tid & 63;
  int cpx = (int)gridDim.x >> 3;
  int sbid = ((int)blockIdx.x & 7) * cpx + ((int)blockIdx.x >> 3);
  int by = sbid / nbx, bx = sbid - by * nbx;
  const int M0 = by * 256, N0 = bx * 256;
  const int wm = w >> 2, wn = w & 3;
  const int fr = lane & 15, fs = lane >> 4;
  const int srow = lane >> 2;
  const int sslot = (lane & 3) ^ ((lane >> 3) & 3);
  const int rsw = (fr >> 1) & 3;

  f32x4 acc[8][4];
  #pragma unroll
  for (int i = 0; i < 8; ++i)
    #pragma unroll
    for (int j = 0; j < 4; ++j) acc[i][j] = {0.f, 0.f, 0.f, 0.f};

  auto STAGE = [&](int t, int buf) {
    int k0 = t * 32;
    #pragma unroll
    for (int j = 0; j < 4; ++j) {
      int c = w * 4 + j;
      if (c < 16)
        gld16(A  + (size_t)(M0 + c * 16 + srow) * 1024 + k0 + sslot * 8,
              &lds[buf][0][c * 512]);
      else
        gld16(Bt + (size_t)(N0 + (c - 16) * 16 + srow) * 1024 + k0 + sslot * 8,
              &lds[buf][1][(c - 16) * 512]);
    }
  };
  auto COMPUTE = [&](int t) {
    const unsigned short* la = &lds[t & 3][0][wm * 128 * 32];
    const unsigned short* lb = &lds[t & 3][1][wn * 64 * 32];
    bf16x8 a[8], b[4];
    #pragma unroll
    for (int ni = 0; ni < 4; ++ni)
      b[ni] = *(const bf16x8*)(lb + (ni * 16 + fr) * 32 + ((fs ^ rsw) * 8));
    #pragma unroll
    for (int mi = 0; mi < 8; ++mi)
      a[mi] = *(const bf16x8*)(la + (mi * 16 + fr) * 32 + ((fs ^ rsw) * 8));
    #pragma unroll
    for (int mi = 0; mi < 8; ++mi)
      #pragma unroll
      for (int ni = 0; ni < 4; ++ni)
        acc[mi][ni] = __builtin_amdgcn_mfma_f32_16x16x32_bf16(a[mi], b[ni], acc[mi][ni], 0, 0, 0);
  };

  STAGE(0, 0); STAGE(1, 1); STAGE(2, 2);
  for (int t = 0; t < 29; ++t) {
    STAGE(t + 3, (t + 3) & 3);
    VMCNT(12);
    bar();
    COMPUTE(t);
    bar();
  }
  VMCNT(8);  bar(); COMPUTE(29); bar();
  VMCNT(4);  bar(); COMPUTE(30); bar();
  VMCNT(0);  bar(); COMPUTE(31);

  if constexpr (EPI == EPI_GELU) {
    #pragma unroll
    for (int mi = 0; mi < 8; ++mi)
      #pragma unroll
      for (int r = 0; r < 4; ++r) {
        size_t m = M0 + wm * 128 + mi * 16 + fs * 4 + r;
        #pragma unroll
        for (int ni = 0; ni < 4; ++ni) {
          int n = N0 + wn * 64 + ni * 16 + fr;
          float v = acc[mi][ni][r] + P.bias[n];
          v = 0.5f * v * (1.f + erff(v * 0.70710678f));
          ((unsigned short*)P.C)[m * P.ldc + n] = f2bf(v);
        }
      }
  } else {  // EPI_QKG / EPI_QG
    const int nb = N0 + wn * 64;
    const bool isQ = nb < 1024;
    const bool isK = (EPI == EPI_QKG) && !isQ && (nb < 2048);
    if (isQ || isK) {
      const float* tc = isK ? P.tab + 262144 : P.tab;
      const float* ts = tc + 131072;
      unsigned short* dst = isK ? P.oK : P.oQ;
      const int nloc = isK ? nb - 1024 : nb;
      const int gsel = (nloc >> 6) & 1;
      #pragma unroll
      for (int mi = 0; mi < 8; ++mi)
        #pragma unroll
        for (int r = 0; r < 4; ++r) {
          size_t m = M0 + wm * 128 + mi * 16 + fs * 4 + r;
          int pos = (int)(m & (SEQQ - 1));
          #pragma unroll
          for (int ni = 0; ni < 2; ++ni) {
            int j = gsel * 32 + ni * 16 + fr;
            float cs = tc[pos * 64 + j], sn = ts[pos * 64 + j];
            float ve = acc[mi][ni][r], vo = acc[mi][ni + 2][r];
            dst[m * 1024 + nloc + ni * 16 + fr]       = f2bf(ve * cs - vo * sn);
            dst[m * 1024 + nloc + (ni + 2) * 16 + fr] = f2bf(vo * cs + ve * sn);
          }
        }
    } else {
      const int nloc = nb - ((EPI == EPI_QKG) ? 2048 : 1024);
      #pragma unroll
      for (int mi = 0; mi < 8; ++mi)
        #pragma unroll
        for (int r = 0; r < 4; ++r) {
          size_t m = M0 + wm * 128 + mi * 16 + fs * 4 + r;
          #pragma unroll
          for (int ni = 0; ni < 4; ++ni) {
            float v = acc[mi][ni][r];
            P.oG[m * 2048 + nloc + ni * 16 + fr] = f2bf(v / (1.f + expf(-v)));
          }
        }
    }
  }
}

// ---- MFMA retention partial v2: 128 q-rows/block (2 halves/wave), bisected -
// 512 blocks. th=bid>>8; th=0: qt descending, th=1: qt ascending (CU pair sums
// to ~constant iters). K/V frags read once, used by both q-halves.
__global__ __launch_bounds__(256) void retention_part(
    const unsigned short* __restrict__ Qx, const unsigned short* __restrict__ Kx,
    const unsigned short* __restrict__ VT,
    unsigned short* __restrict__ Y0, unsigned short* __restrict__ Y1) {
  __shared__ __align__(16) unsigned short Ks[2][32 * 128];
  __shared__ __align__(16) unsigned short Vs[2][256 * 32];
  const int tid = threadIdx.x, w = tid >> 6, lane = tid & 63;
  int bid = blockIdx.x;
  int th = bid >> 8;
  int rr = bid & 255;
  int b  = rr >> 7;
  int rl = rr & 127;
  int qt = th ? (rl >> 3) : (15 - (rl >> 3));
  int h  = rl & 7;
  const int q0 = qt * 128;
  const int fr = lane & 15, fs = lane >> 4;

  float gamma = 1.f - expf(-3.4657359028f - 0.3960841032f * (float)h);
  float l2g = log2f(gamma);       // negative
  const int qA = q0 + w * 16 + fr;
  const int qB = qA + 64;

  size_t rowA = (size_t)b * SEQQ + qA;
  bf16x8 qfA[4], qfB[4];
  #pragma unroll
  for (int ks = 0; ks < 4; ++ks) {
    qfA[ks] = *(const bf16x8*)(Qx + rowA * 1024 + h * 128 + ks * 32 + fs * 8);
    qfB[ks] = *(const bf16x8*)(Qx + (rowA + 64) * 1024 + h * 128 + ks * 32 + fs * 8);
  }

  float gtl8[8];
  #pragma unroll
  for (int i = 0; i < 8; ++i) {
    int toff = (i >> 2) * 16 + fs * 4 + (i & 3);
    gtl8[i] = exp2f(-(float)toff * l2g);
  }

  f32x4 zf = {0.f, 0.f, 0.f, 0.f};
  f32x4 yA[16], yB[16];
  #pragma unroll
  for (int i = 0; i < 16; ++i) { yA[i] = zf; yB[i] = zf; }

  int cutoff = (int)(16.f / (-l2g));
  int t_start = q0 - cutoff;
  if (t_start < 0) t_start = 0;
  t_start &= ~31;
  size_t kbase = (size_t)b * SEQQ;

  auto STAGE = [&](int buf, int t0) {
    #pragma unroll
    for (int c = 0; c < 2; ++c) {
      int ch = w * 2 + c;
      int row = ch * 4 + (lane >> 4);
      int so = (lane & 15) ^ (row & 15);
      gld16(Kx + (kbase + t0 + row) * 1024 + h * 128 + so * 8, &Ks[buf][ch * 512]);
    }
    #pragma unroll
    for (int c = 0; c < 4; ++c) {
      int ch = w * 4 + c;
      int vrow = ch * 16 + (lane >> 2);
      int so = (lane & 3) ^ ((vrow >> 1) & 3);
      gld16(VT + (size_t)(h * 256 + vrow) * RTOT + kbase + t0 + so * 8, &Vs[buf][ch * 512]);
    }
  };

  const int nt_total = (q0 + 128 - t_start) >> 5;   // >= 4
  const int n0 = (nt_total + 1) >> 1;
  const int it0 = th ? n0 : 0;
  const int it1 = th ? nt_total : n0;
  unsigned short* Yp = th ? Y1 : Y0;

  STAGE(0, t_start + it0 * 32);
  int cur = 0;
  for (int it = it0; it < it1; ++it) {
    int t0 = t_start + it * 32;
    if (it + 1 < it1) { STAGE(cur ^ 1, t0 + 32); VMCNT(6); }
    else              { VMCNT(0); }
    bar();

    // S^T = mfma(K, Q) for both q-halves; kf read once
    f32x4 sA[2], sB[2];
    sA[0] = zf; sA[1] = zf; sB[0] = zf; sB[1] = zf;
    #pragma unroll
    for (int nt = 0; nt < 2; ++nt) {
      int row = nt * 16 + fr;
      #pragma unroll
      for (int ks = 0; ks < 4; ++ks) {
        int sl = ks * 4 + fs;
        bf16x8 kf = *(const bf16x8*)(&Ks[cur][row * 128 + (sl ^ (row & 15)) * 8]);
        sA[nt] = __builtin_amdgcn_mfma_f32_16x16x32_bf16(kf, qfA[ks], sA[nt], 0, 0, 0);
        sB[nt] = __builtin_amdgcn_mfma_f32_16x16x32_bf16(kf, qfB[ks], sB[nt], 0, 0, 0);
      }
    }
    // decay + mask + pack, per half
    float fscA = exp2f((float)(qA - t0) * l2g);
    float fscB = exp2f((float)(qB - t0) * l2g);
    uint32 pkA[4], pkB[4];
    #pragma unroll
    for (int nt = 0; nt < 2; ++nt)
      #pragma unroll
      for (int hf = 0; hf < 2; ++hf) {
        int r0i = hf * 2;
        int ta = t0 + nt * 16 + fs * 4 + r0i;
        float g0 = fscA * gtl8[nt * 4 + r0i], g1 = fscA * gtl8[nt * 4 + r0i + 1];
        float va = (qA >= ta)     ? sA[nt][r0i]     * g0 : 0.f;
        float vb = (qA >= ta + 1) ? sA[nt][r0i + 1] * g1 : 0.f;
        pkA[nt * 2 + hf] = (uint32)f2bf(va) | ((uint32)f2bf(vb) << 16);
        float h0 = fscB * gtl8[nt * 4 + r0i], h1 = fscB * gtl8[nt * 4 + r0i + 1];
        float vc = (qB >= ta)     ? sB[nt][r0i]     * h0 : 0.f;
        float vd = (qB >= ta + 1) ? sB[nt][r0i + 1] * h1 : 0.f;
        pkB[nt * 2 + hf] = (uint32)f2bf(vc) | ((uint32)f2bf(vd) << 16);
      }
    union { uint32 u[4]; bf16x8 v8; } paA, paB;
    #pragma unroll
    for (int j = 0; j < 4; ++j) {
      int src = fr + 16 * (2 * (fs & 1) + (j >> 1));
      int a0 = __shfl((int)pkA[j & 1],       src);
      int a1 = __shfl((int)pkA[2 + (j & 1)], src);
      paA.u[j] = (fs < 2) ? (uint32)a0 : (uint32)a1;
      int b0 = __shfl((int)pkB[j & 1],       src);
      int b1 = __shfl((int)pkB[2 + (j & 1)], src);
      paB.u[j] = (fs < 2) ? (uint32)b0 : (uint32)b1;
    }
    // PV for both halves; vf read once
    #pragma unroll
    for (int nv = 0; nv < 16; ++nv) {
      int vrow = nv * 16 + fr;
      bf16x8 vf = *(const bf16x8*)(&Vs[cur][vrow * 32 + (fs ^ ((vrow >> 1) & 3)) * 8]);
      yA[nv] = __builtin_amdgcn_mfma_f32_16x16x32_bf16(paA.v8, vf, yA[nv], 0, 0, 0);
      yB[nv] = __builtin_amdgcn_mfma_f32_16x16x32_bf16(paB.v8, vf, yB[nv], 0, 0, 0);
    }
    bar();
    cur ^= 1;
  }

  // store raw partial Y (both halves) as bf16
  #pragma unroll
  for (int r = 0; r < 4; ++r) {
    int sra = q0 + w * 16 + fs * 4 + r;
    size_t mra = (size_t)b * SEQQ + sra;
    unsigned short* oa = Yp + mra * 2048 + h * 256;
    unsigned short* ob = Yp + (mra + 64) * 2048 + h * 256;
    #pragma unroll
    for (int nv = 0; nv < 16; ++nv) {
      oa[nv * 16 + fr] = f2bf(yA[nv][r]);
      ob[nv * 16 + fr] = f2bf(yB[nv][r]);
    }
  }
}

// ---- combine partials: Y = Y0+Y1; groupnorm(256) * affine * gate -> Gout ---
__global__ __launch_bounds__(256) void combine_gn(
    const unsigned short* __restrict__ Y0, const unsigned short* __restrict__ Y1,
    const unsigned short* __restrict__ Gate,
    const float* __restrict__ gnw, const float* __restrict__ gnb,
    unsigned short* __restrict__ Gout) {
  int idx = blockIdx.x * 4 + (threadIdx.x >> 6);
  int lane = threadIdx.x & 63;
  int h = idx & 7;
  size_t row = (size_t)(idx >> 3);
  size_t base = row * 2048 + h * 256 + lane * 4;
  ushort4 a = *(const ushort4*)(Y0 + base);
  ushort4 bb = *(const ushort4*)(Y1 + base);
  float y0 = bf2f(a.x) + bf2f(bb.x);
  float y1 = bf2f(a.y) + bf2f(bb.y);
  float y2 = bf2f(a.z) + bf2f(bb.z);
  float y3 = bf2f(a.w) + bf2f(bb.w);
  float s  = y0 + y1 + y2 + y3;
  float sq = y0*y0 + y1*y1 + y2*y2 + y3*y3;
  #pragma unroll
  for (int o = 32; o > 0; o >>= 1) { s += __shfl_xor(s, o); sq += __shfl_xor(sq, o); }
  float mu = s * (1.f / 256.f);
  float var = sq * (1.f / 256.f) - mu * mu;
  float rstd = rsqrtf(var + 1e-5f);
  int gi = h * 256 + lane * 4;
  float4 w4 = *(const float4*)(gnw + gi);
  float4 b4 = *(const float4*)(gnb + gi);
  ushort4 g4 = *(const ushort4*)(Gate + base);
  ushort4 o4;
  o4.x = f2bf(bf2f(g4.x) * ((y0 - mu) * rstd * w4.x + b4.x));
  o4.y = f2bf(bf2f(g4.y) * ((y1 - mu) * rstd * w4.y + b4.y));
  o4.z = f2bf(bf2f(g4.z) * ((y2 - mu) * rstd * w4.z + b4.z));
  o4.w = f2bf(bf2f(g4.w) * ((y3 - mu) * rstd * w4.w + b4.w));
  *(ushort4*)(Gout + base) = o4;
}

// =============================== host ========================================
extern "C" void kernel_launch(void* const* d_in, const int* in_sizes, int n_in,
                              void* d_out, int out_size, void* d_ws, size_t ws_size,
                              hipStream_t stream) {
  const float* X    = (const float*)d_in[0];
  const float* mem  = (const float*)d_in[1];
  const float* ln1w = (const float*)d_in[2];
  const float* ln1b = (const float*)d_in[3];
  const float* ln2w = (const float*)d_in[4];
  const float* ln2b = (const float*)d_in[5];
  const float* Wq   = (const float*)d_in[6];
  const float* Wk   = (const float*)d_in[7];
  const float* Wv   = (const float*)d_in[8];
  const float* Wg   = (const float*)d_in[9];
  const float* Wo   = (const float*)d_in[10];
  const float* gnw  = (const float*)d_in[11];
  const float* gnb  = (const float*)d_in[12];
  const float* cWq  = (const float*)d_in[13];
  const float* cWk  = (const float*)d_in[14];
  const float* cWv  = (const float*)d_in[15];
  const float* cWg  = (const float*)d_in[16];
  const float* cWo  = (const float*)d_in[17];
  const float* cgnw = (const float*)d_in[18];
  const float* cgnb = (const float*)d_in[19];
  const float* W1   = (const float*)d_in[20];
  const float* b1   = (const float*)d_in[21];
  const float* W2   = (const float*)d_in[22];
  const float* b2   = (const float*)d_in[23];
  float* out = (float*)d_out;

  const size_t MB = 1024ull * 1024ull;
  if (ws_size < 106 * MB) return;
  unsigned char* W8 = (unsigned char*)d_ws;
  unsigned short* WqkgT = (unsigned short*)(W8 + 0 * MB);
  unsigned short* WvT   = (unsigned short*)(W8 + 8 * MB);
  unsigned short* WoT   = (unsigned short*)(W8 + 12 * MB);
  unsigned short* cQGT  = (unsigned short*)(W8 + 16 * MB);
  unsigned short* cWkT  = (unsigned short*)(W8 + 22 * MB);
  unsigned short* cWvT  = (unsigned short*)(W8 + 24 * MB);
  unsigned short* cWoT  = (unsigned short*)(W8 + 28 * MB);
  float*          tab   = (float*)(W8 + 32 * MB);
  unsigned short* hbuf  = (unsigned short*)(W8 + 34 * MB);
  unsigned short* Qx    = (unsigned short*)(W8 + 42 * MB);
  unsigned short* Kx    = (unsigned short*)(W8 + 50 * MB);
  unsigned short* W1T   = Qx;
  unsigned short* W2T   = Kx;
  unsigned short* VTb   = (unsigned short*)(W8 + 58 * MB);
  unsigned short* Gg    = (unsigned short*)(W8 + 74 * MB);
  unsigned short* Tb    = VTb;
  unsigned short* GoutB = (unsigned short*)(W8 + 90 * MB);
  unsigned short* mem16 = GoutB;
  unsigned short* Yp1a  = (unsigned short*)(W8 + 16 * MB);
  unsigned short* Yp1b  = (unsigned short*)(W8 + 0 * MB);

  EpiP P{};

  // ---- prep1: W transposes + tabgen + LN1(X) ----
  prep1<<<12800, 256, 0, stream>>>(Wq, Wk, Wg, Wv, Wo, WqkgT, WvT, WoT, tab,
                                   X, ln1w, ln1b, hbuf);

  // ---- block 1: self retention ----
  P = EpiP{nullptr, 0, nullptr, nullptr, tab, Qx, Kx, Gg};
  gemm256<EPI_QKG><<<256, 512, 0, stream>>>(hbuf, WqkgT, 16, P);
  P = EpiP{VTb, 4096, nullptr, nullptr, nullptr, nullptr, nullptr, nullptr};
  gemm_mfma<EPI_BF16><<<512, 256, 0, stream>>>(WvT, 1024, hbuf, 1024, 1024, 32, P);
  retention_part<<<dim3(512), 256, 0, stream>>>(Qx, Kx, VTb, GoutB, Yp1a);
  combine_gn<<<RTOT * 2, 256, 0, stream>>>(GoutB, Yp1a, Gg, gnw, gnb, GoutB);
  P = EpiP{out, 1024, nullptr, X, nullptr, nullptr, nullptr, nullptr};
  gemm_bn64<EPI_F32_RES><<<512, 256, 0, stream>>>(GoutB, 2048, WoT, 2048, 2048, 16, P);

  // ---- prep2: cross weights + cvt(mem) + LN2(out) ----
  prep2<<<14336, 256, 0, stream>>>(cWq, cWg, cWk, cWv, cWo, cQGT, cWkT, cWvT, cWoT,
                                   mem, mem16, out, ln2w, ln2b, hbuf);

  // ---- block 2: cross retention ----
  P = EpiP{nullptr, 0, nullptr, nullptr, tab, Qx, nullptr, Gg};
  gemm256<EPI_QG><<<192, 512, 0, stream>>>(hbuf, cQGT, 12, P);
  P = EpiP{Kx, 1024, nullptr, nullptr, tab + 262144, nullptr, nullptr, nullptr};
  gemm_bn64<EPI_XPOS><<<512, 256, 0, stream>>>(mem16, 1024, cWkT, 1024, 1024, 16, P);
  P = EpiP{VTb, 4096, nullptr, nullptr, nullptr, nullptr, nullptr, nullptr};
  gemm_mfma<EPI_BF16><<<512, 256, 0, stream>>>(cWvT, 1024, mem16, 1024, 1024, 32, P);
  retention_part<<<dim3(512), 256, 0, stream>>>(Qx, Kx, VTb, GoutB, Yp1b);
  combine_gn<<<RTOT * 2, 256, 0, stream>>>(GoutB, Yp1b, Gg, cgnw, cgnb, GoutB);
  P = EpiP{out, 1024, nullptr, out, nullptr, nullptr, nullptr, nullptr};
  gemm_bn64<EPI_F32_RES><<<512, 256, 0, stream>>>(GoutB, 2048, cWoT, 2048, 2048, 16, P);

  // ---- prep3: FFN weights + LN2(out) ----
  prep3<<<12288, 256, 0, stream>>>(W1, W2, W1T, W2T, out, ln2w, ln2b, hbuf);

  // ---- FFN ----
  P = EpiP{Tb, 4096, b1, nullptr, nullptr, nullptr, nullptr, nullptr};
  gemm256<EPI_GELU><<<256, 512, 0, stream>>>(hbuf, W1T, 16, P);
  P = EpiP{out, 1024, b2, out, nullptr, nullptr, nullptr, nullptr};
  gemm_bn64<EPI_BRES><<<512, 256, 0, stream>>>(Tb, 4096, W2T, 4096, 4096, 16, P);
}

// Round 16
// 528.382 us; speedup vs baseline: 1.1139x; 1.1139x over previous
//
#include <hip/hip_runtime.h>
#include <math.h>

// Problem: B=2, S=2048, d=1024, h=8, hd=128, hv=256, vd=2048, f=4096
#define RTOT 4096
#define SEQQ 2048

typedef unsigned int uint32;
typedef __attribute__((ext_vector_type(4))) float f32x4;
typedef __attribute__((ext_vector_type(8))) short bf16x8;

__device__ __forceinline__ unsigned short f2bf(float f) {
  unsigned int u = __float_as_uint(f);
  u = (u + 0x7FFFu + ((u >> 16) & 1u)) >> 16;
  return (unsigned short)u;
}
__device__ __forceinline__ float bf2f(unsigned short h) {
  return __uint_as_float(((unsigned int)h) << 16);
}
__device__ __forceinline__ void gld16(const void* g, void* l) {
  __builtin_amdgcn_global_load_lds(
      (const __attribute__((address_space(1))) uint32*)g,
      (__attribute__((address_space(3))) uint32*)l, 16, 0, 0);
}
__device__ __forceinline__ void bar() {
  asm volatile("" ::: "memory");
  __builtin_amdgcn_s_barrier();
  asm volatile("" ::: "memory");
}
#define VMCNT(n) asm volatile("s_waitcnt vmcnt(" #n ")" ::: "memory")

// ---- device transpose tile body: f32[R][C] (+z) -> bf16[C][R], opt. perm ----
__device__ __forceinline__ void tr_tile(
    const float* __restrict__ in, unsigned short* __restrict__ out,
    int R, int C, int perm, int bx, int by, int z) {
  __shared__ float t[32][33];
  in  += (size_t)z * R * C;
  out += (size_t)z * C * R;
  int r0 = bx * 32, c0 = by * 32;
  int tx = threadIdx.x & 31, ty = threadIdx.x >> 5;
  #pragma unroll
  for (int i = 0; i < 4; ++i) {
    int r = ty + i * 8;
    t[r][tx] = in[(size_t)(r0 + r) * C + c0 + tx];
  }
  __syncthreads();
  #pragma unroll
  for (int i = 0; i < 4; ++i) {
    int cc = c0 + ty + i * 8;
    if (perm) cc = 64 * (cc >> 6) + ((cc & 1) << 5) + ((cc & 63) >> 1);
    out[(size_t)cc * R + r0 + tx] = f2bf(t[tx][ty + i * 8]);
  }
}

// ---- tabgen body ----
__device__ __forceinline__ void tab_body(float* __restrict__ tab, int blk) {
  int i = blk * 256 + threadIdx.x;   // 131072
  int pos = i >> 6, j = i & 63;
  float bs = (2.f * (float)j + 51.2f) * (1.f / 179.2f);
  float e = (float)pos * (1.f / 512.f);
  float sc = exp2f(e * log2f(bs));
  float invf = exp2f(-(float)j * (13.287712379549449f / 64.f));
  float su, cu;
  sincosf((float)pos * invf, &su, &cu);
  tab[i]            = cu * sc;
  tab[131072 + i]   = su * sc;
  float si = 1.f / sc;
  tab[262144 + i]   = cu * si;
  tab[393216 + i]   = su * si;
}

// ---- LayerNorm row body ----
__device__ __forceinline__ void ln_row(const float* __restrict__ x,
    const float* __restrict__ w, const float* __restrict__ b,
    unsigned short* __restrict__ out, int row) {
  __shared__ float red[2][4];
  int tid = threadIdx.x;
  const float* xr = x + (size_t)row * 1024;
  float4 v = *(const float4*)(xr + tid * 4);
  float s  = v.x + v.y + v.z + v.w;
  float ss = v.x*v.x + v.y*v.y + v.z*v.z + v.w*v.w;
  #pragma unroll
  for (int o = 32; o > 0; o >>= 1) { s += __shfl_down(s, o); ss += __shfl_down(ss, o); }
  int wid = tid >> 6;
  if ((tid & 63) == 0) { red[0][wid] = s; red[1][wid] = ss; }
  __syncthreads();
  float st  = red[0][0] + red[0][1] + red[0][2] + red[0][3];
  float sst = red[1][0] + red[1][1] + red[1][2] + red[1][3];
  float mu   = st * (1.f / 1024.f);
  float var  = sst * (1.f / 1024.f) - mu * mu;
  float rstd = rsqrtf(var + 1e-5f);
  float4 wv = *(const float4*)(w + tid * 4);
  float4 bv = *(const float4*)(b + tid * 4);
  unsigned short o0 = f2bf((v.x - mu) * rstd * wv.x + bv.x);
  unsigned short o1 = f2bf((v.y - mu) * rstd * wv.y + bv.y);
  unsigned short o2 = f2bf((v.z - mu) * rstd * wv.z + bv.z);
  unsigned short o3 = f2bf((v.w - mu) * rstd * wv.w + bv.w);
  ushort4 o4 = make_ushort4(o0, o1, o2, o3);
  *(ushort4*)(out + (size_t)row * 1024 + tid * 4) = o4;
}

// ---- cvt body ----
__device__ __forceinline__ void cvt_body(const float* __restrict__ in,
    unsigned short* __restrict__ out, int blk) {
  int i = blk * 256 + threadIdx.x;
  const float4* p = (const float4*)(in + (size_t)i * 8);
  float4 a = p[0], b = p[1];
  bf16x8 v;
  v[0] = (short)f2bf(a.x); v[1] = (short)f2bf(a.y); v[2] = (short)f2bf(a.z); v[3] = (short)f2bf(a.w);
  v[4] = (short)f2bf(b.x); v[5] = (short)f2bf(b.y); v[6] = (short)f2bf(b.z); v[7] = (short)f2bf(b.w);
  *(bf16x8*)(out + (size_t)i * 8) = v;
}

// ---- prep1: W transposes + tabgen + LN1(X) in one launch (12800 blocks) ----
__global__ __launch_bounds__(256) void prep1(
    const float* Wq, const float* Wk, const float* Wg, const float* Wv,
    const float* Wo, unsigned short* WqkgT, unsigned short* WvT,
    unsigned short* WoT, float* tab,
    const float* X, const float* ln1w, const float* ln1b, unsigned short* hbuf) {
  int idx = blockIdx.x;
  if (idx < 1024)      { tr_tile(Wq, WqkgT,               1024, 128, 1, idx & 31, (idx >> 5) & 3, idx >> 7); }
  else if (idx < 2048) { int i = idx - 1024; tr_tile(Wk, WqkgT + 1024 * 1024, 1024, 128, 1, i & 31, (i >> 5) & 3, i >> 7); }
  else if (idx < 4096) { int i = idx - 2048; tr_tile(Wg, WqkgT + 2048 * 1024, 1024, 2048, 0, i & 31, i >> 5, 0); }
  else if (idx < 6144) { int i = idx - 4096; tr_tile(Wv, WvT, 1024, 256, 0, i & 31, (i >> 5) & 7, i >> 8); }
  else if (idx < 8192) { int i = idx - 6144; tr_tile(Wo, WoT, 2048, 1024, 0, i & 63, i >> 6, 0); }
  else if (idx < 8704) { tab_body(tab, idx - 8192); }
  else                 { ln_row(X, ln1w, ln1b, hbuf, idx - 8704); }
}

// ---- prep2: cross weights + cvt(mem) + LN2(out) (14336 blocks) ----
__global__ __launch_bounds__(256) void prep2(
    const float* cWq, const float* cWg, const float* cWk, const float* cWv,
    const float* cWo, unsigned short* cQGT, unsigned short* cWkT,
    unsigned short* cWvT, unsigned short* cWoT,
    const float* mem, unsigned short* mem16,
    const float* out, const float* ln2w, const float* ln2b, unsigned short* hbuf) {
  int idx = blockIdx.x;
  if (idx < 1024)       { tr_tile(cWq, cQGT,               1024, 128, 1, idx & 31, (idx >> 5) & 3, idx >> 7); }
  else if (idx < 3072)  { int i = idx - 1024; tr_tile(cWg, cQGT + 1024 * 1024, 1024, 2048, 0, i & 31, i >> 5, 0); }
  else if (idx < 4096)  { int i = idx - 3072; tr_tile(cWk, cWkT, 1024, 128, 1, i & 31, (i >> 5) & 3, i >> 7); }
  else if (idx < 6144)  { int i = idx - 4096; tr_tile(cWv, cWvT, 1024, 256, 0, i & 31, (i >> 5) & 7, i >> 8); }
  else if (idx < 8192)  { int i = idx - 6144; tr_tile(cWo, cWoT, 2048, 1024, 0, i & 63, i >> 6, 0); }
  else if (idx < 10240) { cvt_body(mem, mem16, idx - 8192); }
  else                  { ln_row(out, ln2w, ln2b, hbuf, idx - 10240); }
}

// ---- prep3: FFN weights + LN2(out) (12288 blocks) ----
__global__ __launch_bounds__(256) void prep3(
    const float* W1, const float* W2, unsigned short* W1T, unsigned short* W2T,
    const float* out, const float* ln2w, const float* ln2b, unsigned short* hbuf) {
  int idx = blockIdx.x;
  if (idx < 4096)      { tr_tile(W1, W1T, 1024, 4096, 0, idx & 31, idx >> 5, 0); }
  else if (idx < 8192) { int i = idx - 4096; tr_tile(W2, W2T, 4096, 1024, 0, i & 127, i >> 7, 0); }
  else                 { ln_row(out, ln2w, ln2b, hbuf, idx - 8192); }
}

// ---------------- epilogues ----------------
enum { EPI_F32_RES = 0, EPI_BF16 = 1, EPI_XPOS = 2, EPI_GELU = 4, EPI_BRES = 5,
       EPI_QKG = 6, EPI_QG = 7 };

struct EpiP {
  void* C; int ldc;
  const float* bias; const float* resid;
  const float* tab;
  unsigned short* oQ; unsigned short* oK; unsigned short* oG;
};

template<int EPI>
__device__ __forceinline__ void epi_store(size_t m, int n, int N0, float v, const EpiP& P) {
  if constexpr (EPI == EPI_BF16) {
    ((unsigned short*)P.C)[m * P.ldc + n] = f2bf(v);
  } else if constexpr (EPI == EPI_GELU) {
    v += P.bias[n];
    v = 0.5f * v * (1.f + erff(v * 0.70710678f));
    ((unsigned short*)P.C)[m * P.ldc + n] = f2bf(v);
  } else if constexpr (EPI == EPI_BRES) {
    v += P.bias[n] + P.resid[m * P.ldc + n];
    ((float*)P.C)[m * P.ldc + n] = v;
  } else {  // EPI_F32_RES
    v += P.resid[m * P.ldc + n];
    ((float*)P.C)[m * P.ldc + n] = v;
  }
}

// -- MFMA GEMM 128x128, BK=64 (2 subtiles), dbuf, counted vmcnt, XCD swizzle --
template<int EPI>
__global__ __launch_bounds__(256) void gemm_mfma(
    const unsigned short* __restrict__ A, int lda,
    const unsigned short* __restrict__ Bt, int ldb, int K, int nbx, EpiP P) {
  __shared__ __align__(16) unsigned short As[2][2][128 * 32];
  __shared__ __align__(16) unsigned short Bs[2][2][128 * 32];
  const int tid = threadIdx.x, w = tid >> 6, lane = tid & 63;
  int q8 = (int)gridDim.x >> 3;
  int sbid = ((int)blockIdx.x & 7) * q8 + ((int)blockIdx.x >> 3);
  int by = sbid / nbx, bx = sbid - by * nbx;
  const int M0 = by * 128, N0 = bx * 128;
  const int fr = lane & 15, fs = lane >> 4;
  const int srow = lane >> 2, sp = lane & 3;

  f32x4 zf = {0.f, 0.f, 0.f, 0.f};
  f32x4 acc[4][4];
  #pragma unroll
  for (int i = 0; i < 4; ++i)
    #pragma unroll
    for (int j = 0; j < 4; ++j) acc[i][j] = zf;

  auto STAGE = [&](int buf, int k0) {
    #pragma unroll
    for (int kk = 0; kk < 2; ++kk)
      #pragma unroll
      for (int c = 0; c < 4; ++c) {
        int ch = w * 4 + c;
        int cc = ch & 7;
        int row = cc * 16 + srow;
        int so = sp ^ ((row >> 1) & 3);
        if (ch < 8) gld16(A  + (size_t)(M0 + row) * lda + k0 + kk * 32 + so * 8, &As[buf][kk][cc * 512]);
        else        gld16(Bt + (size_t)(N0 + row) * ldb + k0 + kk * 32 + so * 8, &Bs[buf][kk][cc * 512]);
      }
  };

  const int NT = K >> 6;
  STAGE(0, 0);
  int cur = 0;
  for (int t = 0; t < NT; ++t) {
    if (t + 1 < NT) { STAGE(cur ^ 1, (t + 1) * 64); VMCNT(8); }
    else            { VMCNT(0); }
    bar();
    #pragma unroll
    for (int kk = 0; kk < 2; ++kk) {
      bf16x8 af[4], bfr[4];
      #pragma unroll
      for (int mi = 0; mi < 4; ++mi) {
        int row = (w >> 1) * 64 + mi * 16 + fr;
        af[mi] = *(const bf16x8*)(&As[cur][kk][row * 32 + (fs ^ ((row >> 1) & 3)) * 8]);
      }
      #pragma unroll
      for (int ni = 0; ni < 4; ++ni) {
        int row = (w & 1) * 64 + ni * 16 + fr;
        bfr[ni] = *(const bf16x8*)(&Bs[cur][kk][row * 32 + (fs ^ ((row >> 1) & 3)) * 8]);
      }
      #pragma unroll
      for (int mi = 0; mi < 4; ++mi)
        #pragma unroll
        for (int ni = 0; ni < 4; ++ni)
          acc[mi][ni] = __builtin_amdgcn_mfma_f32_16x16x32_bf16(af[mi], bfr[ni], acc[mi][ni], 0, 0, 0);
    }
    bar();
    cur ^= 1;
  }

  #pragma unroll
  for (int mi = 0; mi < 4; ++mi)
    #pragma unroll
    for (int r = 0; r < 4; ++r) {
      size_t m = M0 + (w >> 1) * 64 + mi * 16 + fs * 4 + r;
      #pragma unroll
      for (int ni = 0; ni < 4; ++ni) {
        int n = N0 + (w & 1) * 64 + ni * 16 + fr;
        epi_store<EPI>(m, n, N0, acc[mi][ni][r], P);
      }
    }
}

// -- MFMA GEMM 128x64, BK=64 (2 subtiles), dbuf, counted vmcnt, XCD swizzle --
template<int EPI>
__global__ __launch_bounds__(256) void gemm_bn64(
    const unsigned short* __restrict__ A, int lda,
    const unsigned short* __restrict__ Bt, int ldb, int K, int nbx, EpiP P) {
  __shared__ __align__(16) unsigned short As[2][2][128 * 32];
  __shared__ __align__(16) unsigned short Bs[2][2][64 * 32];
  const int tid = threadIdx.x, w = tid >> 6, lane = tid & 63;
  int q8 = (int)gridDim.x >> 3;
  int sbid = ((int)blockIdx.x & 7) * q8 + ((int)blockIdx.x >> 3);
  int by = sbid / nbx, bx = sbid - by * nbx;
  const int M0 = by * 128, N0 = bx * 64;
  const int fr = lane & 15, fs = lane >> 4;
  const int srow = lane >> 2, sp = lane & 3;

  f32x4 zf = {0.f, 0.f, 0.f, 0.f};
  f32x4 acc[2][4];
  #pragma unroll
  for (int i = 0; i < 2; ++i)
    #pragma unroll
    for (int j = 0; j < 4; ++j) acc[i][j] = zf;

  auto STAGE = [&](int buf, int k0) {
    #pragma unroll
    for (int kk = 0; kk < 2; ++kk)
      #pragma unroll
      for (int c = 0; c < 3; ++c) {
        int ch = w * 3 + c;
        if (ch < 8) {
          int row = ch * 16 + srow;
          int so = sp ^ ((row >> 1) & 3);
          gld16(A + (size_t)(M0 + row) * lda + k0 + kk * 32 + so * 8, &As[buf][kk][ch * 512]);
        } else {
          int bch = ch - 8;
          int row = bch * 16 + srow;
          int so = sp ^ ((row >> 1) & 3);
          gld16(Bt + (size_t)(N0 + row) * ldb + k0 + kk * 32 + so * 8, &Bs[buf][kk][bch * 512]);
        }
      }
  };

  const int NT = K >> 6;
  STAGE(0, 0);
  int cur = 0;
  for (int t = 0; t < NT; ++t) {
    if (t + 1 < NT) { STAGE(cur ^ 1, (t + 1) * 64); VMCNT(6); }
    else            { VMCNT(0); }
    bar();
    #pragma unroll
    for (int kk = 0; kk < 2; ++kk) {
      bf16x8 af[2], bfr[4];
      #pragma unroll
      for (int mi = 0; mi < 2; ++mi) {
        int row = w * 32 + mi * 16 + fr;
        af[mi] = *(const bf16x8*)(&As[cur][kk][row * 32 + (fs ^ ((row >> 1) & 3)) * 8]);
      }
      #pragma unroll
      for (int ni = 0; ni < 4; ++ni) {
        int row = ni * 16 + fr;
        bfr[ni] = *(const bf16x8*)(&Bs[cur][kk][row * 32 + (fs ^ ((row >> 1) & 3)) * 8]);
      }
      #pragma unroll
      for (int mi = 0; mi < 2; ++mi)
        #pragma unroll
        for (int ni = 0; ni < 4; ++ni)
          acc[mi][ni] = __builtin_amdgcn_mfma_f32_16x16x32_bf16(af[mi], bfr[ni], acc[mi][ni], 0, 0, 0);
    }
    bar();
    cur ^= 1;
  }

  if constexpr (EPI == EPI_XPOS) {
    int gsel = (N0 >> 6) & 1;
    #pragma unroll
    for (int mi = 0; mi < 2; ++mi)
      #pragma unroll
      for (int r = 0; r < 4; ++r) {
        size_t m = M0 + w * 32 + mi * 16 + fs * 4 + r;
        int pos = (int)(m & (SEQQ - 1));
        #pragma unroll
        for (int ni = 0; ni < 2; ++ni) {
          int j = gsel * 32 + ni * 16 + fr;
          float cs = P.tab[pos * 64 + j], sn = P.tab[131072 + pos * 64 + j];
          float ve = acc[mi][ni][r], vo = acc[mi][ni + 2][r];
          unsigned short* dst = (unsigned short*)P.C;
          dst[m * P.ldc + N0 + ni * 16 + fr]       = f2bf(ve * cs - vo * sn);
          dst[m * P.ldc + N0 + (ni + 2) * 16 + fr] = f2bf(vo * cs + ve * sn);
        }
      }
  } else {
    #pragma unroll
    for (int mi = 0; mi < 2; ++mi)
      #pragma unroll
      for (int r = 0; r < 4; ++r) {
        size_t m = M0 + w * 32 + mi * 16 + fs * 4 + r;
        #pragma unroll
        for (int ni = 0; ni < 4; ++ni) {
          int n = N0 + ni * 16 + fr;
          epi_store<EPI>(m, n, N0, acc[mi][ni][r], P);
        }
      }
  }
}

// ---------------- 256x256 8-wave GEMM, 4-deep counted-vmcnt pipeline --------
template<int EPI>
__global__ __launch_bounds__(512, 2) void gemm256(
    const unsigned short* __restrict__ A,
    const unsigned short* __restrict__ Bt,
    int nbx, EpiP P) {
  __shared__ __align__(16) unsigned short lds[4][2][8192];
  const int tid = threadIdx.x, w = tid >> 6, lane = tid & 63;
  int cpx = (int)gridDim.x >> 3;
  int sbid = ((int)blockIdx.x & 7) * cpx + ((int)blockIdx.x >> 3);
  int by = sbid / nbx, bx = sbid - by * nbx;
  const int M0 = by * 256, N0 = bx * 256;
  const int wm = w >> 2, wn = w & 3;
  const int fr = lane & 15, fs = lane >> 4;
  const int srow = lane >> 2;
  const int sslot = (lane & 3) ^ ((lane >> 3) & 3);
  const int rsw = (fr >> 1) & 3;

  f32x4 acc[8][4];
  #pragma unroll
  for (int i = 0; i < 8; ++i)
    #pragma unroll
    for (int j = 0; j < 4; ++j) acc[i][j] = {0.f, 0.f, 0.f, 0.f};

  auto STAGE = [&](int t, int buf) {
    int k0 = t * 32;
    #pragma unroll
    for (int j = 0; j < 4; ++j) {
      int c = w * 4 + j;
      if (c < 16)
        gld16(A  + (size_t)(M0 + c * 16 + srow) * 1024 + k0 + sslot * 8,
              &lds[buf][0][c * 512]);
      else
        gld16(Bt + (size_t)(N0 + (c - 16) * 16 + srow) * 1024 + k0 + sslot * 8,
              &lds[buf][1][(c - 16) * 512]);
    }
  };
  auto COMPUTE = [&](int t) {
    const unsigned short* la = &lds[t & 3][0][wm * 128 * 32];
    const unsigned short* lb = &lds[t & 3][1][wn * 64 * 32];
    bf16x8 a[8], b[4];
    #pragma unroll
    for (int ni = 0; ni < 4; ++ni)
      b[ni] = *(const bf16x8*)(lb + (ni * 16 + fr) * 32 + ((fs ^ rsw) * 8));
    #pragma unroll
    for (int mi = 0; mi < 8; ++mi)
      a[mi] = *(const bf16x8*)(la + (mi * 16 + fr) * 32 + ((fs ^ rsw) * 8));
    #pragma unroll
    for (int mi = 0; mi < 8; ++mi)
      #pragma unroll
      for (int ni = 0; ni < 4; ++ni)
        acc[mi][ni] = __builtin_amdgcn_mfma_f32_16x16x32_bf16(a[mi], b[ni], acc[mi][ni], 0, 0, 0);
  };

  STAGE(0, 0); STAGE(1, 1); STAGE(2, 2);
  for (int t = 0; t < 29; ++t) {
    STAGE(t + 3, (t + 3) & 3);
    VMCNT(12);
    bar();
    COMPUTE(t);
    bar();
  }
  VMCNT(8);  bar(); COMPUTE(29); bar();
  VMCNT(4);  bar(); COMPUTE(30); bar();
  VMCNT(0);  bar(); COMPUTE(31);

  if constexpr (EPI == EPI_GELU) {
    #pragma unroll
    for (int mi = 0; mi < 8; ++mi)
      #pragma unroll
      for (int r = 0; r < 4; ++r) {
        size_t m = M0 + wm * 128 + mi * 16 + fs * 4 + r;
        #pragma unroll
        for (int ni = 0; ni < 4; ++ni) {
          int n = N0 + wn * 64 + ni * 16 + fr;
          float v = acc[mi][ni][r] + P.bias[n];
          v = 0.5f * v * (1.f + erff(v * 0.70710678f));
          ((unsigned short*)P.C)[m * P.ldc + n] = f2bf(v);
        }
      }
  } else {  // EPI_QKG / EPI_QG
    const int nb = N0 + wn * 64;
    const bool isQ = nb < 1024;
    const bool isK = (EPI == EPI_QKG) && !isQ && (nb < 2048);
    if (isQ || isK) {
      const float* tc = isK ? P.tab + 262144 : P.tab;
      const float* ts = tc + 131072;
      unsigned short* dst = isK ? P.oK : P.oQ;
      const int nloc = isK ? nb - 1024 : nb;
      const int gsel = (nloc >> 6) & 1;
      #pragma unroll
      for (int mi = 0; mi < 8; ++mi)
        #pragma unroll
        for (int r = 0; r < 4; ++r) {
          size_t m = M0 + wm * 128 + mi * 16 + fs * 4 + r;
          int pos = (int)(m & (SEQQ - 1));
          #pragma unroll
          for (int ni = 0; ni < 2; ++ni) {
            int j = gsel * 32 + ni * 16 + fr;
            float cs = tc[pos * 64 + j], sn = ts[pos * 64 + j];
            float ve = acc[mi][ni][r], vo = acc[mi][ni + 2][r];
            dst[m * 1024 + nloc + ni * 16 + fr]       = f2bf(ve * cs - vo * sn);
            dst[m * 1024 + nloc + (ni + 2) * 16 + fr] = f2bf(vo * cs + ve * sn);
          }
        }
    } else {
      const int nloc = nb - ((EPI == EPI_QKG) ? 2048 : 1024);
      #pragma unroll
      for (int mi = 0; mi < 8; ++mi)
        #pragma unroll
        for (int r = 0; r < 4; ++r) {
          size_t m = M0 + wm * 128 + mi * 16 + fs * 4 + r;
          #pragma unroll
          for (int ni = 0; ni < 4; ++ni) {
            float v = acc[mi][ni][r];
            P.oG[m * 2048 + nloc + ni * 16 + fr] = f2bf(v / (1.f + expf(-v)));
          }
        }
    }
  }
}

// ---- MFMA retention partial (r14 best): r7 inner loop, t-range bisected ----
__global__ __launch_bounds__(256) void retention_part(
    const unsigned short* __restrict__ Qx, const unsigned short* __restrict__ Kx,
    const unsigned short* __restrict__ VT,
    unsigned short* __restrict__ Y0, unsigned short* __restrict__ Y1) {
  __shared__ __align__(16) unsigned short Ks[2][32 * 128];
  __shared__ __align__(16) unsigned short Vs[2][256 * 32];
  const int tid = threadIdx.x, w = tid >> 6, lane = tid & 63;
  int bid = blockIdx.x;
  int th = bid >> 9;
  int rr = bid & 511;
  int qt, h, b;
  if (rr < 256) { qt = 31 - (rr >> 3); h = rr & 7; b = 0; }
  else          { int k = rr - 256; qt = k >> 3; h = k & 7; b = 1; }
  const int q0 = qt * 64;
  const int fr = lane & 15, fs = lane >> 4;

  float gamma = 1.f - expf(-3.4657359028f - 0.3960841032f * (float)h);
  float l2g = log2f(gamma);
  const int qglob = q0 + w * 16 + fr;

  size_t qrow = (size_t)b * SEQQ + qglob;
  bf16x8 qf[4];
  #pragma unroll
  for (int ks = 0; ks < 4; ++ks)
    qf[ks] = *(const bf16x8*)(Qx + qrow * 1024 + h * 128 + ks * 32 + fs * 8);

  float gtl8[8];
  #pragma unroll
  for (int i = 0; i < 8; ++i) {
    int toff = (i >> 2) * 16 + fs * 4 + (i & 3);
    gtl8[i] = exp2f(-(float)toff * l2g);
  }

  f32x4 zf = {0.f, 0.f, 0.f, 0.f};
  f32x4 yacc[16];
  #pragma unroll
  for (int i = 0; i < 16; ++i) yacc[i] = zf;

  int cutoff = (int)(16.f / (-l2g));
  int t_start = q0 - cutoff;
  if (t_start < 0) t_start = 0;
  t_start &= ~31;
  size_t kbase = (size_t)b * SEQQ;

  auto STAGE = [&](int buf, int t0) {
    #pragma unroll
    for (int c = 0; c < 2; ++c) {
      int ch = w * 2 + c;
      int row = ch * 4 + (lane >> 4);
      int so = (lane & 15) ^ (row & 15);
      gld16(Kx + (kbase + t0 + row) * 1024 + h * 128 + so * 8, &Ks[buf][ch * 512]);
    }
    #pragma unroll
    for (int c = 0; c < 4; ++c) {
      int ch = w * 4 + c;
      int vrow = ch * 16 + (lane >> 2);
      int so = (lane & 3) ^ ((vrow >> 1) & 3);
      gld16(VT + (size_t)(h * 256 + vrow) * RTOT + kbase + t0 + so * 8, &Vs[buf][ch * 512]);
    }
  };

  const int nt_total = (q0 + 64 - t_start) >> 5;
  const int n0 = (nt_total + 1) >> 1;
  const int it0 = th ? n0 : 0;
  const int it1 = th ? nt_total : n0;
  unsigned short* Yp = th ? Y1 : Y0;

  STAGE(0, t_start + it0 * 32);
  int cur = 0;
  for (int it = it0; it < it1; ++it) {
    int t0 = t_start + it * 32;
    if (it + 1 < it1) { STAGE(cur ^ 1, t0 + 32); VMCNT(6); }
    else              { VMCNT(0); }
    bar();

    f32x4 sacc[2];
    sacc[0] = zf; sacc[1] = zf;
    #pragma unroll
    for (int nt = 0; nt < 2; ++nt) {
      int row = nt * 16 + fr;
      #pragma unroll
      for (int ks = 0; ks < 4; ++ks) {
        int sl = ks * 4 + fs;
        bf16x8 kf = *(const bf16x8*)(&Ks[cur][row * 128 + (sl ^ (row & 15)) * 8]);
        sacc[nt] = __builtin_amdgcn_mfma_f32_16x16x32_bf16(kf, qf[ks], sacc[nt], 0, 0, 0);
      }
    }
    float fsc = exp2f((float)(qglob - t0) * l2g);
    uint32 pk[4];
    #pragma unroll
    for (int nt = 0; nt < 2; ++nt)
      #pragma unroll
      for (int hf = 0; hf < 2; ++hf) {
        int r0i = hf * 2;
        int ta = t0 + nt * 16 + fs * 4 + r0i;
        float va = (qglob >= ta)     ? sacc[nt][r0i]     * (fsc * gtl8[nt * 4 + r0i])     : 0.f;
        float vb = (qglob >= ta + 1) ? sacc[nt][r0i + 1] * (fsc * gtl8[nt * 4 + r0i + 1]) : 0.f;
        pk[nt * 2 + hf] = (uint32)f2bf(va) | ((uint32)f2bf(vb) << 16);
      }
    union { uint32 u[4]; bf16x8 v8; } pa;
    #pragma unroll
    for (int j = 0; j < 4; ++j) {
      int src = fr + 16 * (2 * (fs & 1) + (j >> 1));
      int v0 = __shfl((int)pk[j & 1],     src);
      int v1 = __shfl((int)pk[2 + (j & 1)], src);
      pa.u[j] = (fs < 2) ? (uint32)v0 : (uint32)v1;
    }
    #pragma unroll
    for (int nv = 0; nv < 16; ++nv) {
      int vrow = nv * 16 + fr;
      bf16x8 vf = *(const bf16x8*)(&Vs[cur][vrow * 32 + (fs ^ ((vrow >> 1) & 3)) * 8]);
      yacc[nv] = __builtin_amdgcn_mfma_f32_16x16x32_bf16(pa.v8, vf, yacc[nv], 0, 0, 0);
    }
    bar();
    cur ^= 1;
  }

  #pragma unroll
  for (int r = 0; r < 4; ++r) {
    int srow = q0 + w * 16 + fs * 4 + r;
    size_t mrow = (size_t)b * SEQQ + srow;
    unsigned short* orow = Yp + mrow * 2048 + h * 256;
    #pragma unroll
    for (int nv = 0; nv < 16; ++nv)
      orow[nv * 16 + fr] = f2bf(yacc[nv][r]);
  }
}

// ---- combine partials: Y = Y0+Y1; groupnorm(256) * affine * gate -> Gout ---
__global__ __launch_bounds__(256) void combine_gn(
    const unsigned short* __restrict__ Y0, const unsigned short* __restrict__ Y1,
    const unsigned short* __restrict__ Gate,
    const float* __restrict__ gnw, const float* __restrict__ gnb,
    unsigned short* __restrict__ Gout) {
  int idx = blockIdx.x * 4 + (threadIdx.x >> 6);
  int lane = threadIdx.x & 63;
  int h = idx & 7;
  size_t row = (size_t)(idx >> 3);
  size_t base = row * 2048 + h * 256 + lane * 4;
  ushort4 a = *(const ushort4*)(Y0 + base);
  ushort4 bb = *(const ushort4*)(Y1 + base);
  float y0 = bf2f(a.x) + bf2f(bb.x);
  float y1 = bf2f(a.y) + bf2f(bb.y);
  float y2 = bf2f(a.z) + bf2f(bb.z);
  float y3 = bf2f(a.w) + bf2f(bb.w);
  float s  = y0 + y1 + y2 + y3;
  float sq = y0*y0 + y1*y1 + y2*y2 + y3*y3;
  #pragma unroll
  for (int o = 32; o > 0; o >>= 1) { s += __shfl_xor(s, o); sq += __shfl_xor(sq, o); }
  float mu = s * (1.f / 256.f);
  float var = sq * (1.f / 256.f) - mu * mu;
  float rstd = rsqrtf(var + 1e-5f);
  int gi = h * 256 + lane * 4;
  float4 w4 = *(const float4*)(gnw + gi);
  float4 b4 = *(const float4*)(gnb + gi);
  ushort4 g4 = *(const ushort4*)(Gate + base);
  ushort4 o4;
  o4.x = f2bf(bf2f(g4.x) * ((y0 - mu) * rstd * w4.x + b4.x));
  o4.y = f2bf(bf2f(g4.y) * ((y1 - mu) * rstd * w4.y + b4.y));
  o4.z = f2bf(bf2f(g4.z) * ((y2 - mu) * rstd * w4.z + b4.z));
  o4.w = f2bf(bf2f(g4.w) * ((y3 - mu) * rstd * w4.w + b4.w));
  *(ushort4*)(Gout + base) = o4;
}

// =============================== host ========================================
extern "C" void kernel_launch(void* const* d_in, const int* in_sizes, int n_in,
                              void* d_out, int out_size, void* d_ws, size_t ws_size,
                              hipStream_t stream) {
  const float* X    = (const float*)d_in[0];
  const float* mem  = (const float*)d_in[1];
  const float* ln1w = (const float*)d_in[2];
  const float* ln1b = (const float*)d_in[3];
  const float* ln2w = (const float*)d_in[4];
  const float* ln2b = (const float*)d_in[5];
  const float* Wq   = (const float*)d_in[6];
  const float* Wk   = (const float*)d_in[7];
  const float* Wv   = (const float*)d_in[8];
  const float* Wg   = (const float*)d_in[9];
  const float* Wo   = (const float*)d_in[10];
  const float* gnw  = (const float*)d_in[11];
  const float* gnb  = (const float*)d_in[12];
  const float* cWq  = (const float*)d_in[13];
  const float* cWk  = (const float*)d_in[14];
  const float* cWv  = (const float*)d_in[15];
  const float* cWg  = (const float*)d_in[16];
  const float* cWo  = (const float*)d_in[17];
  const float* cgnw = (const float*)d_in[18];
  const float* cgnb = (const float*)d_in[19];
  const float* W1   = (const float*)d_in[20];
  const float* b1   = (const float*)d_in[21];
  const float* W2   = (const float*)d_in[22];
  const float* b2   = (const float*)d_in[23];
  float* out = (float*)d_out;

  const size_t MB = 1024ull * 1024ull;
  if (ws_size < 106 * MB) return;
  unsigned char* W8 = (unsigned char*)d_ws;
  unsigned short* WqkgT = (unsigned short*)(W8 + 0 * MB);
  unsigned short* WvT   = (unsigned short*)(W8 + 8 * MB);
  unsigned short* WoT   = (unsigned short*)(W8 + 12 * MB);
  unsigned short* cQGT  = (unsigned short*)(W8 + 16 * MB);
  unsigned short* cWkT  = (unsigned short*)(W8 + 22 * MB);
  unsigned short* cWvT  = (unsigned short*)(W8 + 24 * MB);
  unsigned short* cWoT  = (unsigned short*)(W8 + 28 * MB);
  float*          tab   = (float*)(W8 + 32 * MB);
  unsigned short* hbuf  = (unsigned short*)(W8 + 34 * MB);
  unsigned short* Qx    = (unsigned short*)(W8 + 42 * MB);
  unsigned short* Kx    = (unsigned short*)(W8 + 50 * MB);
  unsigned short* W1T   = Qx;
  unsigned short* W2T   = Kx;
  unsigned short* VTb   = (unsigned short*)(W8 + 58 * MB);
  unsigned short* Gg    = (unsigned short*)(W8 + 74 * MB);
  unsigned short* Tb    = VTb;
  unsigned short* GoutB = (unsigned short*)(W8 + 90 * MB);
  unsigned short* mem16 = GoutB;
  unsigned short* Yp1a  = (unsigned short*)(W8 + 16 * MB);
  unsigned short* Yp1b  = (unsigned short*)(W8 + 0 * MB);

  EpiP P{};

  // ---- prep1: W transposes + tabgen + LN1(X) ----
  prep1<<<12800, 256, 0, stream>>>(Wq, Wk, Wg, Wv, Wo, WqkgT, WvT, WoT, tab,
                                   X, ln1w, ln1b, hbuf);

  // ---- block 1: self retention ----
  P = EpiP{nullptr, 0, nullptr, nullptr, tab, Qx, Kx, Gg};
  gemm256<EPI_QKG><<<256, 512, 0, stream>>>(hbuf, WqkgT, 16, P);
  P = EpiP{VTb, 4096, nullptr, nullptr, nullptr, nullptr, nullptr, nullptr};
  gemm_mfma<EPI_BF16><<<512, 256, 0, stream>>>(WvT, 1024, hbuf, 1024, 1024, 32, P);
  retention_part<<<dim3(1024), 256, 0, stream>>>(Qx, Kx, VTb, GoutB, Yp1a);
  combine_gn<<<RTOT * 2, 256, 0, stream>>>(GoutB, Yp1a, Gg, gnw, gnb, GoutB);
  P = EpiP{out, 1024, nullptr, X, nullptr, nullptr, nullptr, nullptr};
  gemm_bn64<EPI_F32_RES><<<512, 256, 0, stream>>>(GoutB, 2048, WoT, 2048, 2048, 16, P);

  // ---- prep2: cross weights + cvt(mem) + LN2(out) ----
  prep2<<<14336, 256, 0, stream>>>(cWq, cWg, cWk, cWv, cWo, cQGT, cWkT, cWvT, cWoT,
                                   mem, mem16, out, ln2w, ln2b, hbuf);

  // ---- block 2: cross retention ----
  P = EpiP{nullptr, 0, nullptr, nullptr, tab, Qx, nullptr, Gg};
  gemm256<EPI_QG><<<192, 512, 0, stream>>>(hbuf, cQGT, 12, P);
  P = EpiP{Kx, 1024, nullptr, nullptr, tab + 262144, nullptr, nullptr, nullptr};
  gemm_bn64<EPI_XPOS><<<512, 256, 0, stream>>>(mem16, 1024, cWkT, 1024, 1024, 16, P);
  P = EpiP{VTb, 4096, nullptr, nullptr, nullptr, nullptr, nullptr, nullptr};
  gemm_mfma<EPI_BF16><<<512, 256, 0, stream>>>(cWvT, 1024, mem16, 1024, 1024, 32, P);
  retention_part<<<dim3(1024), 256, 0, stream>>>(Qx, Kx, VTb, GoutB, Yp1b);
  combine_gn<<<RTOT * 2, 256, 0, stream>>>(GoutB, Yp1b, Gg, cgnw, cgnb, GoutB);
  P = EpiP{out, 1024, nullptr, out, nullptr, nullptr, nullptr, nullptr};
  gemm_bn64<EPI_F32_RES><<<512, 256, 0, stream>>>(GoutB, 2048, cWoT, 2048, 2048, 16, P);

  // ---- prep3: FFN weights + LN2(out) ----
  prep3<<<12288, 256, 0, stream>>>(W1, W2, W1T, W2T, out, ln2w, ln2b, hbuf);

  // ---- FFN ----
  P = EpiP{Tb, 4096, b1, nullptr, nullptr, nullptr, nullptr, nullptr};
  gemm256<EPI_GELU><<<256, 512, 0, stream>>>(hbuf, W1T, 16, P);
  P = EpiP{out, 1024, b2, out, nullptr, nullptr, nullptr, nullptr};
  gemm_bn64<EPI_BRES><<<512, 256, 0, stream>>>(Tb, 4096, W2T, 4096, 4096, 16, P);
}